// Round 3
// baseline (617.199 us; speedup 1.0000x reference)
//
#include <hip/hip_runtime.h>
#include <stdint.h>

typedef unsigned short u16;
typedef unsigned int   u32;
typedef unsigned long long u64;

#define F_DIM 256
#define O_DIM 24
#define MARGIN 12.0f
#define CAND_CAP (1u << 21)   // 2M candidates * 4B = 8 MB

#define AS1 __attribute__((address_space(1)))
#define AS3 __attribute__((address_space(3)))

typedef __bf16 bf16x8 __attribute__((ext_vector_type(8)));
typedef float  f32x4  __attribute__((ext_vector_type(4)));

__device__ __forceinline__ u32 ordf(float s) {
    u32 b = __float_as_uint(s);
    return (b & 0x80000000u) ? ~b : (b | 0x80000000u);
}
__device__ __forceinline__ float unordf(u32 u) {
    u32 b = (u & 0x80000000u) ? (u & 0x7FFFFFFFu) : ~u;
    return __uint_as_float(b);
}
__device__ __forceinline__ u16 f2bf(float f) {   // round-to-nearest-even
    u32 u = __float_as_uint(f);
    u32 r = (u + 0x7FFFu + ((u >> 16) & 1u)) >> 16;
    return (u16)r;
}

// ---------------- init ----------------
__global__ void init_kernel(u64* best, u32* rowminU, u32* cand_cnt, int B) {
    int i = blockIdx.x * blockDim.x + threadIdx.x;
    if (i < B) { best[i] = ~0ull; rowminU[i] = 0xFFFFFFFFu; }
    if (i == 0) *cand_cnt = 0u;
}

// ---------------- t2 (fallback path only) ----------------
__global__ void t2_kernel(const float* __restrict__ X, float* __restrict__ t2,
                          int N, int Npad) {
    int tid = threadIdx.x;
    int row = blockIdx.x * 4 + (tid >> 6);
    int lane = tid & 63;
    if (row >= Npad) return;
    if (row >= N) { if (lane == 0) t2[row] = 1e30f; return; }
    float4 v = ((const float4*)(X + (size_t)row * F_DIM))[lane];
    float s = v.x * v.x + v.y * v.y + v.z * v.z + v.w * v.w;
    #pragma unroll
    for (int off = 32; off > 0; off >>= 1) s += __shfl_down(s, off, 64);
    if (lane == 0) t2[row] = s;
}

// ---------------- coalesced tile converter: fp32 row-major -> bf16 fragment order ----------------
// dst tile layout (per 128-row tile): [ks(8)][sub(8)][lane(64)][j(8)]
//   row = sub*16 + (lane&15);  k = ks*32 + (lane>>4)*8 + j
// Fuses t2 (row sumsq) when do_t2 != 0. Both global sides fully coalesced.
__global__ __launch_bounds__(256) void convert_tile(const float* __restrict__ src,
        u16* __restrict__ dst, float* __restrict__ t2out, int nrows, int do_t2) {
    __shared__ u16 tl[32768];
    const int tid = threadIdx.x;
    const int t = blockIdx.x;
    const int w = tid >> 6, L = tid & 63;
    const int col = L * 4;
    const int ks = col >> 5, j = col & 7, lhi = ((col >> 3) & 3) << 4;
    #pragma unroll
    for (int i = 0; i < 32; ++i) {
        int row = i * 4 + w;
        int grow = t * 128 + row;
        float4 v = make_float4(0.f, 0.f, 0.f, 0.f);
        if (grow < nrows) v = *(const float4*)(src + (size_t)grow * F_DIM + col);
        if (do_t2) {
            float s = v.x * v.x + v.y * v.y + v.z * v.z + v.w * v.w;
            #pragma unroll
            for (int off = 32; off > 0; off >>= 1) s += __shfl_down(s, off, 64);
            if (L == 0) t2out[t * 128 + row] = (grow < nrows) ? s : 1e30f;
        }
        u16* p = &tl[ks * 4096 + (row >> 4) * 512 + (((row & 15) | lhi)) * 8 + j];
        p[0] = f2bf(v.x); p[1] = f2bf(v.y); p[2] = f2bf(v.z); p[3] = f2bf(v.w);
    }
    __syncthreads();
    const uint4* s4 = (const uint4*)tl;
    uint4* d4 = (uint4*)(dst + (size_t)t * 32768);
    #pragma unroll
    for (int i = 0; i < 16; ++i) d4[i * 256 + tid] = s4[i * 256 + tid];
}

// ---------------- main: A-in-registers bf16 MFMA + margin candidate capture ----------------
// block = 4 waves stacked in M; wave tile 64(m) x 64(n); block tile 256 x 64.
// B: 64-col N-tiles staged to LDS (32 KB), double buffered, ONE barrier per tile.
__global__ __launch_bounds__(256, 1) void knn_mfma(
    const u16* __restrict__ xbf, const u16* __restrict__ xtbf,
    const float* __restrict__ t2, u32* __restrict__ rowminU,
    u32* __restrict__ cand_cnt, u32* __restrict__ cands,
    int ntiles /*64-col tiles*/, int nch)
{
    __shared__ u16 sB[2][16384];   // 2 x 32 KB

    const int tid = threadIdx.x;
    const int L = tid & 63, w = tid >> 6;
    const int mb = blockIdx.x;           // m-block of 256 rows
    const int chunk = blockIdx.y;
    const int t0 = (int)(((long long)chunk * ntiles) / nch);
    const int t1 = (int)(((long long)(chunk + 1) * ntiles) / nch);

    // ---- stage first B tile (async) ----
    if (t0 < t1) {
        const AS1 u32* gp = (const AS1 u32*)xtbf + (size_t)(t0 >> 1) * 16384 + (size_t)(t0 & 1) * 1024;
        AS3 u32* lb = (AS3 u32*)&sB[0][0];
        #pragma unroll
        for (int ks = 0; ks < 8; ++ks)
            __builtin_amdgcn_global_load_lds(gp + (size_t)ks * 2048 + (size_t)tid * 4,
                                             lb + ks * 1024 + w * 256, 16, 0, 0);
    }

    // ---- load A fragments into registers: wave w owns rows mb*256 + w*64 .. +63 ----
    bf16x8 areg[32];
    {
        const int t128 = mb * 2 + (w >> 1);
        const u16* base = xbf + (size_t)t128 * 32768 + (size_t)((w & 1) * 4) * 512 + (size_t)L * 8;
        #pragma unroll
        for (int ks = 0; ks < 8; ++ks)
            #pragma unroll
            for (int i = 0; i < 4; ++i)
                areg[ks * 4 + i] = *(const bf16x8*)(base + ks * 4096 + i * 512);
    }

    float rowmin_reg[4][4];
    #pragma unroll
    for (int i = 0; i < 4; ++i)
        #pragma unroll
        for (int r = 0; r < 4; ++r) rowmin_reg[i][r] = 1e30f;

    __syncthreads();   // first B tile staged

    for (int nt = t0; nt < t1; ++nt) {
        const int cur = (nt - t0) & 1;
        if (nt + 1 < t1) {   // async stage of next tile into other buffer
            const AS1 u32* gp = (const AS1 u32*)xtbf + (size_t)((nt + 1) >> 1) * 16384
                                + (size_t)((nt + 1) & 1) * 1024;
            AS3 u32* lb = (AS3 u32*)&sB[cur ^ 1][0];
            #pragma unroll
            for (int ks = 0; ks < 8; ++ks)
                __builtin_amdgcn_global_load_lds(gp + (size_t)ks * 2048 + (size_t)tid * 4,
                                                 lb + ks * 1024 + w * 256, 16, 0, 0);
        }

        f32x4 acc[4][4];
        #pragma unroll
        for (int i = 0; i < 4; ++i)
            #pragma unroll
            for (int c = 0; c < 4; ++c)
                #pragma unroll
                for (int r = 0; r < 4; ++r) acc[i][c][r] = 0.f;

        #pragma unroll
        for (int ks = 0; ks < 8; ++ks) {
            bf16x8 bfr[4];
            #pragma unroll
            for (int c = 0; c < 4; ++c)
                bfr[c] = *(const bf16x8*)&sB[cur][ks * 2048 + c * 512 + L * 8];
            #pragma unroll
            for (int i = 0; i < 4; ++i)
                #pragma unroll
                for (int c = 0; c < 4; ++c)
                    acc[i][c] = __builtin_amdgcn_mfma_f32_16x16x32_bf16(areg[ks * 4 + i], bfr[c], acc[i][c], 0, 0, 0);
        }

        // ---- epilogue: scores, running min, margin capture ----
        const int colb = nt * 64 + (L & 15);
        float t2v[4];
        #pragma unroll
        for (int c = 0; c < 4; ++c) t2v[c] = t2[colb + c * 16];

        float r4[4][4];
        #pragma unroll
        for (int i = 0; i < 4; ++i) {
            #pragma unroll
            for (int r = 0; r < 4; ++r) r4[i][r] = 1e30f;
            #pragma unroll
            for (int c = 0; c < 4; ++c)
                #pragma unroll
                for (int r = 0; r < 4; ++r)
                    r4[i][r] = fminf(r4[i][r], fmaf(-2.f, acc[i][c][r], t2v[c]));
        }

        if (nt == t0) {   // seed: exact tile row-min via 16-lane butterfly, publish
            float rr[4][4];
            #pragma unroll
            for (int i = 0; i < 4; ++i)
                #pragma unroll
                for (int r = 0; r < 4; ++r) rr[i][r] = r4[i][r];
            #pragma unroll
            for (int st = 1; st <= 8; st <<= 1)
                #pragma unroll
                for (int i = 0; i < 4; ++i)
                    #pragma unroll
                    for (int r = 0; r < 4; ++r)
                        rr[i][r] = fminf(rr[i][r], __shfl_xor(rr[i][r], st, 64));
            #pragma unroll
            for (int i = 0; i < 4; ++i)
                #pragma unroll
                for (int r = 0; r < 4; ++r) rowmin_reg[i][r] = rr[i][r];
            if ((L & 15) == 0) {
                #pragma unroll
                for (int i = 0; i < 4; ++i)
                    #pragma unroll
                    for (int r = 0; r < 4; ++r)
                        atomicMin(&rowminU[mb * 256 + w * 64 + i * 16 + (L >> 4) * 4 + r],
                                  ordf(rr[i][r]));
            }
        }

        float thr[4][4];
        bool anyhit = false;
        #pragma unroll
        for (int i = 0; i < 4; ++i) {
            const int mrow = mb * 256 + w * 64 + i * 16 + (L >> 4) * 4;
            uint4 gm = *(const uint4*)&rowminU[mrow];   // stale-OK (only loosens)
            u32 gmv[4] = {gm.x, gm.y, gm.z, gm.w};
            #pragma unroll
            for (int r = 0; r < 4; ++r) {
                float v = fminf(fminf(rowmin_reg[i][r], r4[i][r]), unordf(gmv[r]));
                rowmin_reg[i][r] = v;
                thr[i][r] = v + MARGIN;
                anyhit = anyhit || (r4[i][r] < thr[i][r]);
            }
        }
        if (__any(anyhit)) {   // rare wave-level slow path
            #pragma unroll
            for (int i = 0; i < 4; ++i) {
                #pragma unroll
                for (int r = 0; r < 4; ++r) {
                    if (r4[i][r] < thr[i][r]) {
                        const int q = mb * 256 + w * 64 + i * 16 + (L >> 4) * 4 + r;
                        #pragma unroll
                        for (int c = 0; c < 4; ++c) {
                            float s = fmaf(-2.f, acc[i][c][r], t2v[c]);
                            if (s < thr[i][r]) {
                                int n = colb + c * 16;
                                u32 idx = atomicAdd(cand_cnt, 1u);
                                if (idx < CAND_CAP) cands[idx] = ((u32)q << 16) | (u32)n;
                                atomicMin(&rowminU[q], ordf(s));
                            }
                        }
                    }
                }
            }
        }
        __syncthreads();   // drains next-tile stage (issued ~2000 cyc ago) + buffer reuse
    }
}

// ---------------- exact fp32 rescore of captured candidates, one wave each ----------------
__global__ void rescore(const float* __restrict__ x, const float* __restrict__ Xt,
                        const float* __restrict__ t2, const u32* __restrict__ cand_cnt,
                        const u32* __restrict__ cands, u64* __restrict__ best) {
    const int L = threadIdx.x & 63;
    const int wid = blockIdx.x * (blockDim.x >> 6) + (threadIdx.x >> 6);
    const int nw = gridDim.x * (blockDim.x >> 6);
    u32 cnt = *cand_cnt;
    if (cnt > CAND_CAP) cnt = CAND_CAP;
    for (u32 idx = wid; idx < cnt; idx += nw) {
        u32 u = cands[idx];
        int q = (int)(u >> 16), n = (int)(u & 0xFFFFu);
        float4 xv = *(const float4*)(x  + (size_t)q * F_DIM + L * 4);
        float4 tv = *(const float4*)(Xt + (size_t)n * F_DIM + L * 4);
        float d = fmaf(xv.x, tv.x, fmaf(xv.y, tv.y, fmaf(xv.z, tv.z, xv.w * tv.w)));
        #pragma unroll
        for (int st = 32; st > 0; st >>= 1) d += __shfl_xor(d, st, 64);
        if (L == 0) {
            float s = fmaf(-2.f, d, t2[n]);
            u64 p = ((u64)ordf(s) << 32) | (u32)n;
            atomicMin(&best[q], p);
        }
    }
}

// ---------------- gather Y[nearest] ----------------
__global__ void gather_kernel(const float* __restrict__ Y, const u64* __restrict__ best,
                              float* __restrict__ out, int B, int N) {
    int gid = blockIdx.x * blockDim.x + threadIdx.x;
    int total = B * O_DIM;
    if (gid >= total) return;
    int b = gid / O_DIM;
    int o = gid - b * O_DIM;
    u32 n = (u32)(best[b] & 0xFFFFFFFFull);
    if (n >= (u32)N) n = 0;   // defensive
    out[gid] = Y[(size_t)n * O_DIM + o];
}

// ================= fp32 fallback (proven Round-1 path, used if ws too small) =================
#define BM 128
#define BN 128
#define BK 16
#define NSPLIT 64
#define LDA (BM + 4)

__global__ __launch_bounds__(256) void knn_main_fp32(
    const float* __restrict__ Xq, const float* __restrict__ Xt,
    const float* __restrict__ t2, u64* __restrict__ best, int N)
{
    __shared__ float As[BK][LDA];
    __shared__ float Bs[BK][LDA];
    __shared__ u64 red[BM][17];

    const int tid = threadIdx.x;
    const int tx = tid & 15;
    const int ty = tid >> 4;
    const int m0 = blockIdx.y * BM;
    const int CHUNK = (N + NSPLIT - 1) / NSPLIT;
    const int n0c = blockIdx.x * CHUNK;
    const int n1c = min(N, n0c + CHUNK);

    u64 bestv[8];
    #pragma unroll
    for (int i = 0; i < 8; ++i) bestv[i] = ~0ull;

    const int srow = tid >> 2;
    const int scol4 = (tid & 3) * 4;

    for (int nt = n0c; nt < n1c; nt += BN) {
        float accl[8][8];
        #pragma unroll
        for (int i = 0; i < 8; ++i)
            #pragma unroll
            for (int j = 0; j < 8; ++j) accl[i][j] = 0.f;
        for (int k0 = 0; k0 < F_DIM; k0 += BK) {
            #pragma unroll
            for (int h = 0; h < 2; ++h) {
                int row = h * 64 + srow;
                float4 av = *(const float4*)(Xq + (size_t)(m0 + row) * F_DIM + k0 + scol4);
                As[scol4 + 0][row] = av.x; As[scol4 + 1][row] = av.y;
                As[scol4 + 2][row] = av.z; As[scol4 + 3][row] = av.w;
                int n = nt + row;
                float4 bv = make_float4(0.f, 0.f, 0.f, 0.f);
                if (n < n1c) bv = *(const float4*)(Xt + (size_t)n * F_DIM + k0 + scol4);
                Bs[scol4 + 0][row] = bv.x; Bs[scol4 + 1][row] = bv.y;
                Bs[scol4 + 2][row] = bv.z; Bs[scol4 + 3][row] = bv.w;
            }
            __syncthreads();
            #pragma unroll
            for (int k = 0; k < BK; ++k) {
                float4 a0 = *(const float4*)&As[k][ty * 4];
                float4 a1 = *(const float4*)&As[k][64 + ty * 4];
                float4 b0 = *(const float4*)&Bs[k][tx * 4];
                float4 b1 = *(const float4*)&Bs[k][64 + tx * 4];
                float am[8] = {a0.x, a0.y, a0.z, a0.w, a1.x, a1.y, a1.z, a1.w};
                float bn[8] = {b0.x, b0.y, b0.z, b0.w, b1.x, b1.y, b1.z, b1.w};
                #pragma unroll
                for (int i = 0; i < 8; ++i)
                    #pragma unroll
                    for (int j = 0; j < 8; ++j)
                        accl[i][j] = fmaf(am[i], bn[j], accl[i][j]);
            }
            __syncthreads();
        }
        #pragma unroll
        for (int j = 0; j < 8; ++j) {
            int nl = (j < 4) ? (tx * 4 + j) : (64 + tx * 4 + (j - 4));
            int n = nt + nl;
            if (n < n1c) {
                float t2v = t2[n];
                #pragma unroll
                for (int i = 0; i < 8; ++i) {
                    float score = fmaf(-2.f, accl[i][j], t2v);
                    u64 p = ((u64)ordf(score) << 32) | (u32)n;
                    bestv[i] = (p < bestv[i]) ? p : bestv[i];
                }
            }
        }
    }
    #pragma unroll
    for (int i = 0; i < 8; ++i) {
        int ml = (i < 4) ? (ty * 4 + i) : (64 + ty * 4 + (i - 4));
        red[ml][tx] = bestv[i];
    }
    __syncthreads();
    if (tid < BM) {
        u64 b = red[tid][0];
        #pragma unroll
        for (int t = 1; t < 16; ++t) { u64 v = red[tid][t]; b = (v < b) ? v : b; }
        atomicMin(&best[m0 + tid], b);
    }
}

// ================= launch =================
extern "C" void kernel_launch(void* const* d_in, const int* in_sizes, int n_in,
                              void* d_out, int out_size, void* d_ws, size_t ws_size,
                              hipStream_t stream) {
    const float* x  = (const float*)d_in[0];
    const float* Xt = (const float*)d_in[1];
    const float* Yt = (const float*)d_in[2];
    float* out = (float*)d_out;

    const int B = in_sizes[0] / F_DIM;        // 2048
    const int N = in_sizes[1] / F_DIM;        // 50000
    const int NT128 = (N + 127) / 128;        // 391
    const int Npad = NT128 * 128;             // 50048
    const int NT64 = NT128 * 2;               // 782
    const int MB = B / 256;                   // 8
    const int MT128 = B / 128;                // 16
    const int NCH = 32;

    char* wsp = (char*)d_ws;
    size_t off = 0;
    auto nxt = [&](size_t bytes) {
        char* p = wsp + off;
        off = (off + bytes + 255) & ~(size_t)255;
        return p;
    };
    float* t2      = (float*)nxt((size_t)Npad * 4);
    u32*   rowmin  = (u32*)  nxt((size_t)B * 4);
    u64*   best    = (u64*)  nxt((size_t)B * 8);
    u32*   cnt     = (u32*)  nxt(256);
    u32*   cands   = (u32*)  nxt((size_t)CAND_CAP * 4);
    u16*   xbf     = (u16*)  nxt((size_t)B * F_DIM * 2);
    u16*   xtbf    = (u16*)  nxt((size_t)Npad * F_DIM * 2);
    size_t required = off;

    init_kernel<<<(B + 255) / 256, 256, 0, stream>>>(best, rowmin, cnt, B);

    if (ws_size >= required && B % 256 == 0) {
        // fast path: bf16 MFMA (A-in-regs) + exact margin-rescue
        convert_tile<<<MT128, 256, 0, stream>>>(x, xbf, (float*)nullptr, B, 0);
        convert_tile<<<NT128, 256, 0, stream>>>(Xt, xtbf, t2, N, 1);   // fused t2
        knn_mfma<<<dim3(MB, NCH), 256, 0, stream>>>(xbf, xtbf, t2, rowmin, cnt, cands, NT64, NCH);
        rescore<<<512, 256, 0, stream>>>(x, Xt, t2, cnt, cands, best);
    } else {
        // fallback: proven fp32 VALU path
        t2_kernel<<<(N + 3) / 4, 256, 0, stream>>>(Xt, t2, N, N);
        dim3 grid(NSPLIT, B / BM);
        knn_main_fp32<<<grid, 256, 0, stream>>>(x, Xt, t2, best, N);
    }

    int total = B * O_DIM;
    gather_kernel<<<(total + 255) / 256, 256, 0, stream>>>(Yt, best, out, B, N);
}

// Round 4
// 409.458 us; speedup vs baseline: 1.5074x; 1.5074x over previous
//
#include <hip/hip_runtime.h>
#include <stdint.h>

typedef unsigned short u16;
typedef unsigned int   u32;
typedef unsigned long long u64;

#define F_DIM 256
#define O_DIM 24
#define MARGIN 6.0f
#define CAND_CAP (1u << 21)   // 2M candidates * 4B = 8 MB

#define AS1 __attribute__((address_space(1)))
#define AS3 __attribute__((address_space(3)))

typedef __bf16 bf16x8 __attribute__((ext_vector_type(8)));
typedef float  f32x4  __attribute__((ext_vector_type(4)));

__device__ __forceinline__ u32 ordf(float s) {
    u32 b = __float_as_uint(s);
    return (b & 0x80000000u) ? ~b : (b | 0x80000000u);
}
__device__ __forceinline__ float unordf(u32 u) {
    u32 b = (u & 0x80000000u) ? (u & 0x7FFFFFFFu) : ~u;
    return __uint_as_float(b);
}
__device__ __forceinline__ u16 f2bf(float f) {   // round-to-nearest-even
    u32 u = __float_as_uint(f);
    u32 r = (u + 0x7FFFu + ((u >> 16) & 1u)) >> 16;
    return (u16)r;
}

// ---------------- init ----------------
__global__ void init_kernel(u64* best, u32* rowminU, u32* cand_cnt, int B) {
    int i = blockIdx.x * blockDim.x + threadIdx.x;
    if (i < B) { best[i] = ~0ull; rowminU[i] = 0xFFFFFFFFu; }
    if (i == 0) *cand_cnt = 0u;
}

// ---------------- t2 (fallback path only) ----------------
__global__ void t2_kernel(const float* __restrict__ X, float* __restrict__ t2,
                          int N, int Npad) {
    int tid = threadIdx.x;
    int row = blockIdx.x * 4 + (tid >> 6);
    int lane = tid & 63;
    if (row >= Npad) return;
    if (row >= N) { if (lane == 0) t2[row] = 1e30f; return; }
    float4 v = ((const float4*)(X + (size_t)row * F_DIM))[lane];
    float s = v.x * v.x + v.y * v.y + v.z * v.z + v.w * v.w;
    #pragma unroll
    for (int off = 32; off > 0; off >>= 1) s += __shfl_down(s, off, 64);
    if (lane == 0) t2[row] = s;
}

// ---------------- coalesced tile converter: fp32 row-major -> bf16 fragment order ----------------
// dst tile layout (per 128-row tile): [ks(8)][sub(8)][lane(64)][j(8)]
//   row = sub*16 + (lane&15);  k = ks*32 + (lane>>4)*8 + j
__global__ __launch_bounds__(256) void convert_tile(const float* __restrict__ src,
        u16* __restrict__ dst, float* __restrict__ t2out, int nrows, int do_t2) {
    __shared__ u16 tl[32768];
    const int tid = threadIdx.x;
    const int t = blockIdx.x;
    const int w = tid >> 6, L = tid & 63;
    const int col = L * 4;
    const int ks = col >> 5, j = col & 7, lhi = ((col >> 3) & 3) << 4;
    #pragma unroll
    for (int i = 0; i < 32; ++i) {
        int row = i * 4 + w;
        int grow = t * 128 + row;
        float4 v = make_float4(0.f, 0.f, 0.f, 0.f);
        if (grow < nrows) v = *(const float4*)(src + (size_t)grow * F_DIM + col);
        if (do_t2) {
            float s = v.x * v.x + v.y * v.y + v.z * v.z + v.w * v.w;
            #pragma unroll
            for (int off = 32; off > 0; off >>= 1) s += __shfl_down(s, off, 64);
            if (L == 0) t2out[t * 128 + row] = (grow < nrows) ? s : 1e30f;
        }
        u16* p = &tl[ks * 4096 + (row >> 4) * 512 + (((row & 15) | lhi)) * 8 + j];
        p[0] = f2bf(v.x); p[1] = f2bf(v.y); p[2] = f2bf(v.z); p[3] = f2bf(v.w);
    }
    __syncthreads();
    const uint4* s4 = (const uint4*)tl;
    uint4* d4 = (uint4*)(dst + (size_t)t * 32768);
    #pragma unroll
    for (int i = 0; i < 16; ++i) d4[i * 256 + tid] = s4[i * 256 + tid];
}

// ---------------- main: A-in-registers bf16 MFMA + aggregated margin capture ----------------
// block = 4 waves stacked in M; wave tile 64(m) x 64(n); block tile 256 x 64.
// B: 64-col N-tiles staged to LDS (32 KB), double buffered, ONE barrier per tile.
__global__ __launch_bounds__(256, 2) void knn_mfma(
    const u16* __restrict__ xbf, const u16* __restrict__ xtbf,
    const float* __restrict__ t2, u32* rowminU,
    u32* cand_cnt, u32* __restrict__ cands,
    int ntiles /*64-col tiles*/, int nch)
{
    __shared__ u16 sB[2][16384];   // 2 x 32 KB

    const int tid = threadIdx.x;
    const int L = tid & 63, w = tid >> 6;
    const int mb = blockIdx.x;           // m-block of 256 rows
    const int chunk = blockIdx.y;
    const int t0 = (int)(((long long)chunk * ntiles) / nch);
    const int t1 = (int)(((long long)(chunk + 1) * ntiles) / nch);

    // ---- stage first B tile (async) ----
    if (t0 < t1) {
        const AS1 u32* gp = (const AS1 u32*)xtbf + (size_t)(t0 >> 1) * 16384 + (size_t)(t0 & 1) * 1024;
        AS3 u32* lb = (AS3 u32*)&sB[0][0];
        #pragma unroll
        for (int ks = 0; ks < 8; ++ks)
            __builtin_amdgcn_global_load_lds(gp + (size_t)ks * 2048 + (size_t)tid * 4,
                                             lb + ks * 1024 + w * 256, 16, 0, 0);
    }

    // ---- load A fragments into registers: wave w owns rows mb*256 + w*64 .. +63 ----
    bf16x8 areg[32];
    {
        const int t128 = mb * 2 + (w >> 1);
        const u16* base = xbf + (size_t)t128 * 32768 + (size_t)((w & 1) * 4) * 512 + (size_t)L * 8;
        #pragma unroll
        for (int ks = 0; ks < 8; ++ks)
            #pragma unroll
            for (int i = 0; i < 4; ++i)
                areg[ks * 4 + i] = *(const bf16x8*)(base + ks * 4096 + i * 512);
    }

    float rowmin_reg[4][4];
    #pragma unroll
    for (int i = 0; i < 4; ++i)
        #pragma unroll
        for (int r = 0; r < 4; ++r) rowmin_reg[i][r] = 1e30f;

    __syncthreads();   // first B tile staged

    for (int nt = t0; nt < t1; ++nt) {
        const int cur = (nt - t0) & 1;
        if (nt + 1 < t1) {   // async stage of next tile into other buffer
            const AS1 u32* gp = (const AS1 u32*)xtbf + (size_t)((nt + 1) >> 1) * 16384
                                + (size_t)((nt + 1) & 1) * 1024;
            AS3 u32* lb = (AS3 u32*)&sB[cur ^ 1][0];
            #pragma unroll
            for (int ks = 0; ks < 8; ++ks)
                __builtin_amdgcn_global_load_lds(gp + (size_t)ks * 2048 + (size_t)tid * 4,
                                                 lb + ks * 1024 + w * 256, 16, 0, 0);
        }

        f32x4 acc[4][4];
        #pragma unroll
        for (int i = 0; i < 4; ++i)
            #pragma unroll
            for (int c = 0; c < 4; ++c)
                #pragma unroll
                for (int r = 0; r < 4; ++r) acc[i][c][r] = 0.f;

        #pragma unroll
        for (int ks = 0; ks < 8; ++ks) {
            bf16x8 bfr[4];
            #pragma unroll
            for (int c = 0; c < 4; ++c)
                bfr[c] = *(const bf16x8*)&sB[cur][ks * 2048 + c * 512 + L * 8];
            #pragma unroll
            for (int i = 0; i < 4; ++i)
                #pragma unroll
                for (int c = 0; c < 4; ++c)
                    acc[i][c] = __builtin_amdgcn_mfma_f32_16x16x32_bf16(areg[ks * 4 + i], bfr[c], acc[i][c], 0, 0, 0);
        }

        // ---- epilogue ----
        const int colb = nt * 64 + (L & 15);
        float t2v[4];
        #pragma unroll
        for (int c = 0; c < 4; ++c) t2v[c] = t2[colb + c * 16];

        float r4[4][4];   // per (msub, reg): min over the 4 n-subtiles
        #pragma unroll
        for (int i = 0; i < 4; ++i) {
            #pragma unroll
            for (int r = 0; r < 4; ++r) r4[i][r] = 1e30f;
            #pragma unroll
            for (int c = 0; c < 4; ++c)
                #pragma unroll
                for (int r = 0; r < 4; ++r)
                    r4[i][r] = fminf(r4[i][r], fmaf(-2.f, acc[i][c][r], t2v[c]));
        }

        // fold global rowmin (stale-OK: only loosens) + local tile mins
        #pragma unroll
        for (int i = 0; i < 4; ++i) {
            const int mrow = mb * 256 + w * 64 + i * 16 + (L >> 4) * 4;
            uint4 gm = *(const uint4*)&rowminU[mrow];
            rowmin_reg[i][0] = fminf(fminf(rowmin_reg[i][0], r4[i][0]), unordf(gm.x));
            rowmin_reg[i][1] = fminf(fminf(rowmin_reg[i][1], r4[i][1]), unordf(gm.y));
            rowmin_reg[i][2] = fminf(fminf(rowmin_reg[i][2], r4[i][2]), unordf(gm.z));
            rowmin_reg[i][3] = fminf(fminf(rowmin_reg[i][3], r4[i][3]), unordf(gm.w));
        }

        // every 4th tile: butterfly to true row-min across the 16 col-lanes, publish
        if (((nt - t0) & 3) == 0) {
            #pragma unroll
            for (int st = 1; st <= 8; st <<= 1)
                #pragma unroll
                for (int i = 0; i < 4; ++i)
                    #pragma unroll
                    for (int r = 0; r < 4; ++r)
                        rowmin_reg[i][r] = fminf(rowmin_reg[i][r], __shfl_xor(rowmin_reg[i][r], st, 64));
            if ((L & 15) == 0) {   // fire-and-forget publishes (no return dependency)
                #pragma unroll
                for (int i = 0; i < 4; ++i)
                    #pragma unroll
                    for (int r = 0; r < 4; ++r)
                        atomicMin(&rowminU[mb * 256 + w * 64 + i * 16 + (L >> 4) * 4 + r],
                                  ordf(rowmin_reg[i][r]));
            }
        }

        // ---- aggregated capture: one atomicAdd per wave per hit-tile ----
        bool anyhit = false;
        #pragma unroll
        for (int i = 0; i < 4; ++i)
            #pragma unroll
            for (int r = 0; r < 4; ++r)
                anyhit = anyhit || (r4[i][r] < rowmin_reg[i][r] + MARGIN);

        if (__any(anyhit)) {
            // pass 1: per-lane hit count
            u32 cnt = 0;
            #pragma unroll
            for (int i = 0; i < 4; ++i)
                #pragma unroll
                for (int r = 0; r < 4; ++r) {
                    float th = rowmin_reg[i][r] + MARGIN;
                    if (r4[i][r] < th) {
                        #pragma unroll
                        for (int c = 0; c < 4; ++c)
                            cnt += (fmaf(-2.f, acc[i][c][r], t2v[c]) < th) ? 1u : 0u;
                    }
                }
            // inclusive prefix sum over 64 lanes
            u32 pre = cnt;
            #pragma unroll
            for (int d = 1; d < 64; d <<= 1) {
                u32 v = __shfl_up(pre, d, 64);
                if (L >= d) pre += v;
            }
            u32 total = __shfl(pre, 63, 64);
            u32 base = 0;
            if (L == 63 && total) base = atomicAdd(cand_cnt, total);
            base = __shfl(base, 63, 64);
            u32 woff = base + pre - cnt;
            // pass 2: emit
            #pragma unroll
            for (int i = 0; i < 4; ++i)
                #pragma unroll
                for (int r = 0; r < 4; ++r) {
                    float th = rowmin_reg[i][r] + MARGIN;
                    if (r4[i][r] < th) {
                        const int q = mb * 256 + w * 64 + i * 16 + (L >> 4) * 4 + r;
                        atomicMin(&rowminU[q], ordf(r4[i][r]));   // fire-and-forget
                        #pragma unroll
                        for (int c = 0; c < 4; ++c) {
                            if (fmaf(-2.f, acc[i][c][r], t2v[c]) < th) {
                                if (woff < CAND_CAP)
                                    cands[woff] = ((u32)q << 16) | (u32)(colb + c * 16);
                                woff++;
                            }
                        }
                    }
                }
        }
        __syncthreads();   // drains next-tile stage + protects buffer reuse
    }
}

// ---------------- exact fp32 rescore of captured candidates, one wave each ----------------
__global__ void rescore(const float* __restrict__ x, const float* __restrict__ Xt,
                        const float* __restrict__ t2, const u32* __restrict__ cand_cnt,
                        const u32* __restrict__ cands, u64* __restrict__ best) {
    const int L = threadIdx.x & 63;
    const int wid = blockIdx.x * (blockDim.x >> 6) + (threadIdx.x >> 6);
    const int nw = gridDim.x * (blockDim.x >> 6);
    u32 cnt = *cand_cnt;
    if (cnt > CAND_CAP) cnt = CAND_CAP;
    for (u32 idx = wid; idx < cnt; idx += nw) {
        u32 u = cands[idx];
        int q = (int)(u >> 16), n = (int)(u & 0xFFFFu);
        float4 xv = *(const float4*)(x  + (size_t)q * F_DIM + L * 4);
        float4 tv = *(const float4*)(Xt + (size_t)n * F_DIM + L * 4);
        float d = fmaf(xv.x, tv.x, fmaf(xv.y, tv.y, fmaf(xv.z, tv.z, xv.w * tv.w)));
        #pragma unroll
        for (int st = 32; st > 0; st >>= 1) d += __shfl_xor(d, st, 64);
        if (L == 0) {
            float s = fmaf(-2.f, d, t2[n]);
            u64 p = ((u64)ordf(s) << 32) | (u32)n;
            atomicMin(&best[q], p);
        }
    }
}

// ---------------- gather Y[nearest] ----------------
__global__ void gather_kernel(const float* __restrict__ Y, const u64* __restrict__ best,
                              float* __restrict__ out, int B, int N) {
    int gid = blockIdx.x * blockDim.x + threadIdx.x;
    int total = B * O_DIM;
    if (gid >= total) return;
    int b = gid / O_DIM;
    int o = gid - b * O_DIM;
    u32 n = (u32)(best[b] & 0xFFFFFFFFull);
    if (n >= (u32)N) n = 0;   // defensive
    out[gid] = Y[(size_t)n * O_DIM + o];
}

// ================= fp32 fallback (proven Round-1 path, used if ws too small) =================
#define BM 128
#define BN 128
#define BK 16
#define NSPLIT 64
#define LDA (BM + 4)

__global__ __launch_bounds__(256) void knn_main_fp32(
    const float* __restrict__ Xq, const float* __restrict__ Xt,
    const float* __restrict__ t2, u64* __restrict__ best, int N)
{
    __shared__ float As[BK][LDA];
    __shared__ float Bs[BK][LDA];
    __shared__ u64 red[BM][17];

    const int tid = threadIdx.x;
    const int tx = tid & 15;
    const int ty = tid >> 4;
    const int m0 = blockIdx.y * BM;
    const int CHUNK = (N + NSPLIT - 1) / NSPLIT;
    const int n0c = blockIdx.x * CHUNK;
    const int n1c = min(N, n0c + CHUNK);

    u64 bestv[8];
    #pragma unroll
    for (int i = 0; i < 8; ++i) bestv[i] = ~0ull;

    const int srow = tid >> 2;
    const int scol4 = (tid & 3) * 4;

    for (int nt = n0c; nt < n1c; nt += BN) {
        float accl[8][8];
        #pragma unroll
        for (int i = 0; i < 8; ++i)
            #pragma unroll
            for (int j = 0; j < 8; ++j) accl[i][j] = 0.f;
        for (int k0 = 0; k0 < F_DIM; k0 += BK) {
            #pragma unroll
            for (int h = 0; h < 2; ++h) {
                int row = h * 64 + srow;
                float4 av = *(const float4*)(Xq + (size_t)(m0 + row) * F_DIM + k0 + scol4);
                As[scol4 + 0][row] = av.x; As[scol4 + 1][row] = av.y;
                As[scol4 + 2][row] = av.z; As[scol4 + 3][row] = av.w;
                int n = nt + row;
                float4 bv = make_float4(0.f, 0.f, 0.f, 0.f);
                if (n < n1c) bv = *(const float4*)(Xt + (size_t)n * F_DIM + k0 + scol4);
                Bs[scol4 + 0][row] = bv.x; Bs[scol4 + 1][row] = bv.y;
                Bs[scol4 + 2][row] = bv.z; Bs[scol4 + 3][row] = bv.w;
            }
            __syncthreads();
            #pragma unroll
            for (int k = 0; k < BK; ++k) {
                float4 a0 = *(const float4*)&As[k][ty * 4];
                float4 a1 = *(const float4*)&As[k][64 + ty * 4];
                float4 b0 = *(const float4*)&Bs[k][tx * 4];
                float4 b1 = *(const float4*)&Bs[k][64 + tx * 4];
                float am[8] = {a0.x, a0.y, a0.z, a0.w, a1.x, a1.y, a1.z, a1.w};
                float bn[8] = {b0.x, b0.y, b0.z, b0.w, b1.x, b1.y, b1.z, b1.w};
                #pragma unroll
                for (int i = 0; i < 8; ++i)
                    #pragma unroll
                    for (int j = 0; j < 8; ++j)
                        accl[i][j] = fmaf(am[i], bn[j], accl[i][j]);
            }
            __syncthreads();
        }
        #pragma unroll
        for (int j = 0; j < 8; ++j) {
            int nl = (j < 4) ? (tx * 4 + j) : (64 + tx * 4 + (j - 4));
            int n = nt + nl;
            if (n < n1c) {
                float t2v = t2[n];
                #pragma unroll
                for (int i = 0; i < 8; ++i) {
                    float score = fmaf(-2.f, accl[i][j], t2v);
                    u64 p = ((u64)ordf(score) << 32) | (u32)n;
                    bestv[i] = (p < bestv[i]) ? p : bestv[i];
                }
            }
        }
    }
    #pragma unroll
    for (int i = 0; i < 8; ++i) {
        int ml = (i < 4) ? (ty * 4 + i) : (64 + ty * 4 + (i - 4));
        red[ml][tx] = bestv[i];
    }
    __syncthreads();
    if (tid < BM) {
        u64 b = red[tid][0];
        #pragma unroll
        for (int t = 1; t < 16; ++t) { u64 v = red[tid][t]; b = (v < b) ? v : b; }
        atomicMin(&best[m0 + tid], b);
    }
}

// ================= launch =================
extern "C" void kernel_launch(void* const* d_in, const int* in_sizes, int n_in,
                              void* d_out, int out_size, void* d_ws, size_t ws_size,
                              hipStream_t stream) {
    const float* x  = (const float*)d_in[0];
    const float* Xt = (const float*)d_in[1];
    const float* Yt = (const float*)d_in[2];
    float* out = (float*)d_out;

    const int B = in_sizes[0] / F_DIM;        // 2048
    const int N = in_sizes[1] / F_DIM;        // 50000
    const int NT128 = (N + 127) / 128;        // 391
    const int Npad = NT128 * 128;             // 50048
    const int NT64 = NT128 * 2;               // 782
    const int MB = B / 256;                   // 8
    const int MT128 = B / 128;                // 16
    const int NCH = 64;                       // 8*64 = 512 blocks = 2/CU

    char* wsp = (char*)d_ws;
    size_t off = 0;
    auto nxt = [&](size_t bytes) {
        char* p = wsp + off;
        off = (off + bytes + 255) & ~(size_t)255;
        return p;
    };
    float* t2      = (float*)nxt((size_t)Npad * 4);
    u32*   rowmin  = (u32*)  nxt((size_t)B * 4);
    u64*   best    = (u64*)  nxt((size_t)B * 8);
    u32*   cnt     = (u32*)  nxt(256);
    u32*   cands   = (u32*)  nxt((size_t)CAND_CAP * 4);
    u16*   xbf     = (u16*)  nxt((size_t)B * F_DIM * 2);
    u16*   xtbf    = (u16*)  nxt((size_t)Npad * F_DIM * 2);
    size_t required = off;

    init_kernel<<<(B + 255) / 256, 256, 0, stream>>>(best, rowmin, cnt, B);

    if (ws_size >= required && B % 256 == 0) {
        // fast path: bf16 MFMA (A-in-regs) + exact margin-rescue
        convert_tile<<<MT128, 256, 0, stream>>>(x, xbf, (float*)nullptr, B, 0);
        convert_tile<<<NT128, 256, 0, stream>>>(Xt, xtbf, t2, N, 1);   // fused t2
        knn_mfma<<<dim3(MB, NCH), 256, 0, stream>>>(xbf, xtbf, t2, rowmin, cnt, cands, NT64, NCH);
        rescore<<<512, 256, 0, stream>>>(x, Xt, t2, cnt, cands, best);
    } else {
        // fallback: proven fp32 VALU path
        t2_kernel<<<(N + 3) / 4, 256, 0, stream>>>(Xt, t2, N, N);
        dim3 grid(NSPLIT, B / BM);
        knn_main_fp32<<<grid, 256, 0, stream>>>(x, Xt, t2, best, N);
    }

    int total = B * O_DIM;
    gather_kernel<<<(total + 255) / 256, 256, 0, stream>>>(Yt, best, out, B, N);
}

// Round 5
// 332.513 us; speedup vs baseline: 1.8562x; 1.2314x over previous
//
#include <hip/hip_runtime.h>
#include <stdint.h>

typedef unsigned short u16;
typedef unsigned int   u32;
typedef unsigned long long u64;

#define F_DIM 256
#define O_DIM 24
#define MARGIN 3.0f
#define WCAP 1024            // candidate slots per capture-wave (4 KB each)
#define NWAVE_CAP 2048       // 8 mb * 64 chunks * 4 waves

#define AS1 __attribute__((address_space(1)))
#define AS3 __attribute__((address_space(3)))

typedef __bf16 bf16x8 __attribute__((ext_vector_type(8)));
typedef float  f32x4  __attribute__((ext_vector_type(4)));

__device__ __forceinline__ u32 ordf(float s) {
    u32 b = __float_as_uint(s);
    return (b & 0x80000000u) ? ~b : (b | 0x80000000u);
}
__device__ __forceinline__ u16 f2bf(float f) {   // round-to-nearest-even
    u32 u = __float_as_uint(f);
    u32 r = (u + 0x7FFFu + ((u >> 16) & 1u)) >> 16;
    return (u16)r;
}

// ---------------- init ----------------
__global__ void init_kernel(u64* best, u32* wavecnt, int B) {
    int i = blockIdx.x * blockDim.x + threadIdx.x;
    if (i < B) best[i] = ~0ull;
    if (i < NWAVE_CAP) wavecnt[i] = 0u;
}

// ---------------- t2 (fallback path only) ----------------
__global__ void t2_kernel(const float* __restrict__ X, float* __restrict__ t2,
                          int N, int Npad) {
    int tid = threadIdx.x;
    int row = blockIdx.x * 4 + (tid >> 6);
    int lane = tid & 63;
    if (row >= Npad) return;
    if (row >= N) { if (lane == 0) t2[row] = 1e30f; return; }
    float4 v = ((const float4*)(X + (size_t)row * F_DIM))[lane];
    float s = v.x * v.x + v.y * v.y + v.z * v.z + v.w * v.w;
    #pragma unroll
    for (int off = 32; off > 0; off >>= 1) s += __shfl_down(s, off, 64);
    if (lane == 0) t2[row] = s;
}

// ---------------- coalesced converter: fp32 row-major -> bf16 fragment order ----------------
// dst tile layout (per 128-row tile): [ks(8)][sub(8)][lane(64)][j(8)]
//   row = sub*16 + (lane&15);  k = ks*32 + (lane>>4)*8 + j
// grid = (tiles, 4): block handles 32 rows. Fuses t2 when do_t2.
__global__ __launch_bounds__(256) void convert_tile(const float* __restrict__ src,
        u16* __restrict__ dst, float* __restrict__ t2out, int nrows, int do_t2) {
    __shared__ u16 tl[8192];   // 16 KB: [ks(8)][subl(2)][lane(64)][j(8)]
    const int tid = threadIdx.x;
    const int t = blockIdx.x, p = blockIdx.y;
    const int w = tid >> 6, L = tid & 63;
    const int col = L * 4;
    const int ks = col >> 5, j = col & 7, lhi = ((col >> 3) & 3) << 4;
    #pragma unroll
    for (int i = 0; i < 8; ++i) {
        int rloc = i * 4 + w;                 // 0..31
        int grow = t * 128 + p * 32 + rloc;
        float4 v = make_float4(0.f, 0.f, 0.f, 0.f);
        if (grow < nrows) v = *(const float4*)(src + (size_t)grow * F_DIM + col);
        if (do_t2) {
            float s = v.x * v.x + v.y * v.y + v.z * v.z + v.w * v.w;
            #pragma unroll
            for (int off = 32; off > 0; off >>= 1) s += __shfl_down(s, off, 64);
            if (L == 0) t2out[grow] = (grow < nrows) ? s : 1e30f;
        }
        u16* q = &tl[ks * 1024 + (rloc >> 4) * 512 + (((rloc & 15) | lhi)) * 8 + j];
        q[0] = f2bf(v.x); q[1] = f2bf(v.y); q[2] = f2bf(v.z); q[3] = f2bf(v.w);
    }
    __syncthreads();
    const uint4* s4 = (const uint4*)tl;
    uint4* d4 = (uint4*)(dst + (size_t)t * 32768);
    #pragma unroll
    for (int v = 0; v < 4; ++v) {
        int lin = v * 256 + tid;              // 0..1023
        int ksc = lin >> 7, subl = (lin >> 6) & 1, lane = lin & 63;
        d4[(ksc * 8 + 2 * p + subl) * 64 + lane] = s4[lin];
    }
}

// ---------------- main: A-in-registers bf16 MFMA, chunk-local capture, NO atomics ----------------
__global__ __launch_bounds__(256, 2) void knn_mfma(
    const u16* __restrict__ xbf, const u16* __restrict__ xtbf,
    const float* __restrict__ t2, u32* __restrict__ wavecnt,
    u32* __restrict__ cands, int ntiles /*64-col tiles*/, int nch)
{
    __shared__ u16 sB[2][16384];   // 2 x 32 KB

    const int tid = threadIdx.x;
    const int L = tid & 63, w = tid >> 6;
    const int mb = blockIdx.x;           // m-block of 256 rows (8)
    const int chunk = blockIdx.y;        // (64)
    const int gwave = (chunk * gridDim.x + mb) * 4 + w;
    const int t0 = (int)(((long long)chunk * ntiles) / nch);
    const int t1 = (int)(((long long)(chunk + 1) * ntiles) / nch);

    // ---- stage first B tile (async) ----
    {
        const AS1 u32* gp = (const AS1 u32*)xtbf + (size_t)(t0 >> 1) * 16384 + (size_t)(t0 & 1) * 1024;
        AS3 u32* lb = (AS3 u32*)&sB[0][0];
        #pragma unroll
        for (int ks = 0; ks < 8; ++ks)
            __builtin_amdgcn_global_load_lds(gp + (size_t)ks * 2048 + (size_t)tid * 4,
                                             lb + ks * 1024 + w * 256, 16, 0, 0);
    }

    // ---- A fragments in registers: wave w owns rows mb*256 + w*64 .. +63 ----
    bf16x8 areg[32];
    {
        const int t128 = mb * 2 + (w >> 1);
        const u16* base = xbf + (size_t)t128 * 32768 + (size_t)((w & 1) * 4) * 512 + (size_t)L * 8;
        #pragma unroll
        for (int ks = 0; ks < 8; ++ks)
            #pragma unroll
            for (int i = 0; i < 4; ++i)
                areg[ks * 4 + i] = *(const bf16x8*)(base + ks * 4096 + i * 512);
    }

    float rowmin_reg[4][4];
    #pragma unroll
    for (int i = 0; i < 4; ++i)
        #pragma unroll
        for (int r = 0; r < 4; ++r) rowmin_reg[i][r] = 1e30f;

    u32 wcount = 0;                       // wave-uniform candidate cursor
    u32* const wreg = cands + (size_t)gwave * WCAP;

    __syncthreads();   // first B tile staged

    for (int nt = t0; nt < t1; ++nt) {
        const int cur = (nt - t0) & 1;
        if (nt + 1 < t1) {   // async stage of next tile into other buffer
            const AS1 u32* gp = (const AS1 u32*)xtbf + (size_t)((nt + 1) >> 1) * 16384
                                + (size_t)((nt + 1) & 1) * 1024;
            AS3 u32* lb = (AS3 u32*)&sB[cur ^ 1][0];
            #pragma unroll
            for (int ks = 0; ks < 8; ++ks)
                __builtin_amdgcn_global_load_lds(gp + (size_t)ks * 2048 + (size_t)tid * 4,
                                                 lb + ks * 1024 + w * 256, 16, 0, 0);
        }

        f32x4 acc[4][4];
        #pragma unroll
        for (int i = 0; i < 4; ++i)
            #pragma unroll
            for (int c = 0; c < 4; ++c)
                #pragma unroll
                for (int r = 0; r < 4; ++r) acc[i][c][r] = 0.f;

        #pragma unroll
        for (int ks = 0; ks < 8; ++ks) {
            bf16x8 bfr[4];
            #pragma unroll
            for (int c = 0; c < 4; ++c)
                bfr[c] = *(const bf16x8*)&sB[cur][ks * 2048 + c * 512 + L * 8];
            #pragma unroll
            for (int i = 0; i < 4; ++i)
                #pragma unroll
                for (int c = 0; c < 4; ++c)
                    acc[i][c] = __builtin_amdgcn_mfma_f32_16x16x32_bf16(areg[ks * 4 + i], bfr[c], acc[i][c], 0, 0, 0);
        }

        // ---- epilogue ----
        const int colb = nt * 64 + (L & 15);
        float t2v[4];
        #pragma unroll
        for (int c = 0; c < 4; ++c) t2v[c] = t2[colb + c * 16];

        float r4[4][4];   // per-lane min over its 4 n-subtiles
        #pragma unroll
        for (int i = 0; i < 4; ++i) {
            #pragma unroll
            for (int r = 0; r < 4; ++r) r4[i][r] = 1e30f;
            #pragma unroll
            for (int c = 0; c < 4; ++c)
                #pragma unroll
                for (int r = 0; r < 4; ++r)
                    r4[i][r] = fminf(r4[i][r], fmaf(-2.f, acc[i][c][r], t2v[c]));
        }

        // butterfly current tile's row-min across the 16 col-lanes; fold into running min
        {
            float tm[4][4];
            #pragma unroll
            for (int i = 0; i < 4; ++i)
                #pragma unroll
                for (int r = 0; r < 4; ++r) tm[i][r] = r4[i][r];
            #pragma unroll
            for (int st = 1; st <= 8; st <<= 1)
                #pragma unroll
                for (int i = 0; i < 4; ++i)
                    #pragma unroll
                    for (int r = 0; r < 4; ++r)
                        tm[i][r] = fminf(tm[i][r], __shfl_xor(tm[i][r], st, 64));
            #pragma unroll
            for (int i = 0; i < 4; ++i)
                #pragma unroll
                for (int r = 0; r < 4; ++r)
                    rowmin_reg[i][r] = fminf(rowmin_reg[i][r], tm[i][r]);
        }

        bool anyhit = false;
        #pragma unroll
        for (int i = 0; i < 4; ++i)
            #pragma unroll
            for (int r = 0; r < 4; ++r)
                anyhit = anyhit || (r4[i][r] < rowmin_reg[i][r] + MARGIN);

        if (__any(anyhit)) {
            // pass 1: per-lane hit count
            u32 cnt = 0;
            #pragma unroll
            for (int i = 0; i < 4; ++i)
                #pragma unroll
                for (int r = 0; r < 4; ++r) {
                    float th = rowmin_reg[i][r] + MARGIN;
                    if (r4[i][r] < th) {
                        #pragma unroll
                        for (int c = 0; c < 4; ++c)
                            cnt += (fmaf(-2.f, acc[i][c][r], t2v[c]) < th) ? 1u : 0u;
                    }
                }
            // inclusive prefix sum over 64 lanes
            u32 pre = cnt;
            #pragma unroll
            for (int d = 1; d < 64; d <<= 1) {
                u32 v = __shfl_up(pre, d, 64);
                if (L >= d) pre += v;
            }
            u32 total = __shfl(pre, 63, 64);
            u32 woff = wcount + pre - cnt;
            // pass 2: emit to the wave-private region (no atomics)
            #pragma unroll
            for (int i = 0; i < 4; ++i)
                #pragma unroll
                for (int r = 0; r < 4; ++r) {
                    float th = rowmin_reg[i][r] + MARGIN;
                    if (r4[i][r] < th) {
                        const int q = mb * 256 + w * 64 + i * 16 + (L >> 4) * 4 + r;
                        #pragma unroll
                        for (int c = 0; c < 4; ++c) {
                            if (fmaf(-2.f, acc[i][c][r], t2v[c]) < th) {
                                if (woff < WCAP)
                                    wreg[woff] = ((u32)q << 16) | (u32)(colb + c * 16);
                                woff++;
                            }
                        }
                    }
                }
            wcount += total;
        }
        __syncthreads();   // drains next-tile stage (issued ~2000 cyc ago) + buffer reuse
    }

    if (L == 0) wavecnt[gwave] = (wcount < WCAP) ? wcount : WCAP;
}

// ---------------- exact fp32 rescore: 16 lanes per candidate, 4 in flight per wave ----------------
__global__ void rescore(const float* __restrict__ x, const float* __restrict__ Xt,
                        const float* __restrict__ t2, const u32* __restrict__ wavecnt,
                        const u32* __restrict__ cands, u64* __restrict__ best) {
    const int L = threadIdx.x & 63;
    const int grp = L >> 4, l16 = L & 15;
    const int gw = blockIdx.x * (blockDim.x >> 6) + (threadIdx.x >> 6);
    if (gw >= NWAVE_CAP) return;
    u32 cnt = wavecnt[gw];
    const u32* reg = cands + (size_t)gw * WCAP;
    for (u32 i = grp; i < cnt; i += 4) {
        u32 u = reg[i];
        int q = (int)(u >> 16), n = (int)(u & 0xFFFFu);
        const float4* xp = (const float4*)(x  + (size_t)q * F_DIM) + l16 * 4;
        const float4* tp = (const float4*)(Xt + (size_t)n * F_DIM) + l16 * 4;
        float d = 0.f;
        #pragma unroll
        for (int v = 0; v < 4; ++v) {
            float4 a = xp[v], b = tp[v];
            d = fmaf(a.x, b.x, d); d = fmaf(a.y, b.y, d);
            d = fmaf(a.z, b.z, d); d = fmaf(a.w, b.w, d);
        }
        #pragma unroll
        for (int st = 1; st <= 8; st <<= 1) d += __shfl_xor(d, st, 16);
        if (l16 == 0) {
            float s = fmaf(-2.f, d, t2[n]);
            u64 p = ((u64)ordf(s) << 32) | (u32)n;
            atomicMin(&best[q], p);
        }
    }
}

// ---------------- gather Y[nearest] ----------------
__global__ void gather_kernel(const float* __restrict__ Y, const u64* __restrict__ best,
                              float* __restrict__ out, int B, int N) {
    int gid = blockIdx.x * blockDim.x + threadIdx.x;
    int total = B * O_DIM;
    if (gid >= total) return;
    int b = gid / O_DIM;
    int o = gid - b * O_DIM;
    u32 n = (u32)(best[b] & 0xFFFFFFFFull);
    if (n >= (u32)N) n = 0;   // defensive
    out[gid] = Y[(size_t)n * O_DIM + o];
}

// ================= fp32 fallback (proven Round-1 path, used if ws too small) =================
#define BM 128
#define BN 128
#define BK 16
#define NSPLIT 64
#define LDA (BM + 4)

__global__ __launch_bounds__(256) void knn_main_fp32(
    const float* __restrict__ Xq, const float* __restrict__ Xt,
    const float* __restrict__ t2, u64* __restrict__ best, int N)
{
    __shared__ float As[BK][LDA];
    __shared__ float Bs[BK][LDA];
    __shared__ u64 red[BM][17];

    const int tid = threadIdx.x;
    const int tx = tid & 15;
    const int ty = tid >> 4;
    const int m0 = blockIdx.y * BM;
    const int CHUNK = (N + NSPLIT - 1) / NSPLIT;
    const int n0c = blockIdx.x * CHUNK;
    const int n1c = min(N, n0c + CHUNK);

    u64 bestv[8];
    #pragma unroll
    for (int i = 0; i < 8; ++i) bestv[i] = ~0ull;

    const int srow = tid >> 2;
    const int scol4 = (tid & 3) * 4;

    for (int nt = n0c; nt < n1c; nt += BN) {
        float accl[8][8];
        #pragma unroll
        for (int i = 0; i < 8; ++i)
            #pragma unroll
            for (int j = 0; j < 8; ++j) accl[i][j] = 0.f;
        for (int k0 = 0; k0 < F_DIM; k0 += BK) {
            #pragma unroll
            for (int h = 0; h < 2; ++h) {
                int row = h * 64 + srow;
                float4 av = *(const float4*)(Xq + (size_t)(m0 + row) * F_DIM + k0 + scol4);
                As[scol4 + 0][row] = av.x; As[scol4 + 1][row] = av.y;
                As[scol4 + 2][row] = av.z; As[scol4 + 3][row] = av.w;
                int n = nt + row;
                float4 bv = make_float4(0.f, 0.f, 0.f, 0.f);
                if (n < n1c) bv = *(const float4*)(Xt + (size_t)n * F_DIM + k0 + scol4);
                Bs[scol4 + 0][row] = bv.x; Bs[scol4 + 1][row] = bv.y;
                Bs[scol4 + 2][row] = bv.z; Bs[scol4 + 3][row] = bv.w;
            }
            __syncthreads();
            #pragma unroll
            for (int k = 0; k < BK; ++k) {
                float4 a0 = *(const float4*)&As[k][ty * 4];
                float4 a1 = *(const float4*)&As[k][64 + ty * 4];
                float4 b0 = *(const float4*)&Bs[k][tx * 4];
                float4 b1 = *(const float4*)&Bs[k][64 + tx * 4];
                float am[8] = {a0.x, a0.y, a0.z, a0.w, a1.x, a1.y, a1.z, a1.w};
                float bn[8] = {b0.x, b0.y, b0.z, b0.w, b1.x, b1.y, b1.z, b1.w};
                #pragma unroll
                for (int i = 0; i < 8; ++i)
                    #pragma unroll
                    for (int j = 0; j < 8; ++j)
                        accl[i][j] = fmaf(am[i], bn[j], accl[i][j]);
            }
            __syncthreads();
        }
        #pragma unroll
        for (int j = 0; j < 8; ++j) {
            int nl = (j < 4) ? (tx * 4 + j) : (64 + tx * 4 + (j - 4));
            int n = nt + nl;
            if (n < n1c) {
                float t2v = t2[n];
                #pragma unroll
                for (int i = 0; i < 8; ++i) {
                    float score = fmaf(-2.f, accl[i][j], t2v);
                    u64 p = ((u64)ordf(score) << 32) | (u32)n;
                    bestv[i] = (p < bestv[i]) ? p : bestv[i];
                }
            }
        }
    }
    #pragma unroll
    for (int i = 0; i < 8; ++i) {
        int ml = (i < 4) ? (ty * 4 + i) : (64 + ty * 4 + (i - 4));
        red[ml][tx] = bestv[i];
    }
    __syncthreads();
    if (tid < BM) {
        u64 b = red[tid][0];
        #pragma unroll
        for (int t = 1; t < 16; ++t) { u64 v = red[tid][t]; b = (v < b) ? v : b; }
        atomicMin(&best[m0 + tid], b);
    }
}

// ================= launch =================
extern "C" void kernel_launch(void* const* d_in, const int* in_sizes, int n_in,
                              void* d_out, int out_size, void* d_ws, size_t ws_size,
                              hipStream_t stream) {
    const float* x  = (const float*)d_in[0];
    const float* Xt = (const float*)d_in[1];
    const float* Yt = (const float*)d_in[2];
    float* out = (float*)d_out;

    const int B = in_sizes[0] / F_DIM;        // 2048
    const int N = in_sizes[1] / F_DIM;        // 50000
    const int NT128 = (N + 127) / 128;        // 391
    const int Npad = NT128 * 128;             // 50048
    const int NT64 = NT128 * 2;               // 782
    const int MB = B / 256;                   // 8
    const int MT128 = B / 128;                // 16
    const int NCH = 64;                       // 8*64 = 512 blocks = 2/CU

    char* wsp = (char*)d_ws;
    size_t off = 0;
    auto nxt = [&](size_t bytes) {
        char* p = wsp + off;
        off = (off + bytes + 255) & ~(size_t)255;
        return p;
    };
    float* t2      = (float*)nxt((size_t)Npad * 4);
    u64*   best    = (u64*)  nxt((size_t)B * 8);
    u32*   wavecnt = (u32*)  nxt((size_t)NWAVE_CAP * 4);
    u32*   cands   = (u32*)  nxt((size_t)NWAVE_CAP * WCAP * 4);
    u16*   xbf     = (u16*)  nxt((size_t)B * F_DIM * 2);
    u16*   xtbf    = (u16*)  nxt((size_t)Npad * F_DIM * 2);
    size_t required = off;

    init_kernel<<<(NWAVE_CAP + 255) / 256, 256, 0, stream>>>(best, wavecnt, B);

    if (ws_size >= required && B % 256 == 0 && MB * NCH * 4 <= NWAVE_CAP) {
        // fast path: bf16 MFMA (A-in-regs, atomic-free capture) + exact margin-rescue
        convert_tile<<<dim3(MT128, 4), 256, 0, stream>>>(x, xbf, (float*)nullptr, B, 0);
        convert_tile<<<dim3(NT128, 4), 256, 0, stream>>>(Xt, xtbf, t2, N, 1);   // fused t2
        knn_mfma<<<dim3(MB, NCH), 256, 0, stream>>>(xbf, xtbf, t2, wavecnt, cands, NT64, NCH);
        rescore<<<512, 256, 0, stream>>>(x, Xt, t2, wavecnt, cands, best);
    } else {
        // fallback: proven fp32 VALU path
        t2_kernel<<<(N + 3) / 4, 256, 0, stream>>>(Xt, t2, N, N);
        dim3 grid(NSPLIT, B / BM);
        knn_main_fp32<<<grid, 256, 0, stream>>>(x, Xt, t2, best, N);
    }

    int total = B * O_DIM;
    gather_kernel<<<(total + 255) / 256, 256, 0, stream>>>(Yt, best, out, B, N);
}